// Round 3
// baseline (162.598 us; speedup 1.0000x reference)
//
#include <hip/hip_runtime.h>

#define T_STEPS 512
#define BATCH   8192

typedef float f32x2 __attribute__((ext_vector_type(2)));

__device__ __forceinline__ float bperm(int byteIdx, float v) {
    return __int_as_float(__builtin_amdgcn_ds_bpermute(byteIdx, __float_as_int(v)));
}
__device__ __forceinline__ float rcp_hw(float v)  { return __builtin_amdgcn_rcpf(v); }
__device__ __forceinline__ float exp2_hw(float v) { return __builtin_amdgcn_exp2f(v); }

// acc = wpk * broadcast(b.lo) + acc   (both halves use b's LOW register)
__device__ __forceinline__ void pk_fma_lo(f32x2& d, f32x2 a, f32x2 b) {
    asm("v_pk_fma_f32 %0, %1, %2, %0 op_sel:[0,0,0] op_sel_hi:[1,0,1]"
        : "+v"(d) : "v"(a), "v"(b));
}
// acc = wpk * broadcast(b.hi) + acc   (both halves use b's HIGH register)
__device__ __forceinline__ void pk_fma_hi(f32x2& d, f32x2 a, f32x2 b) {
    asm("v_pk_fma_f32 %0, %1, %2, %0 op_sel:[0,1,0] op_sel_hi:[1,1,1]"
        : "+v"(d) : "v"(a), "v"(b));
}

__device__ __forceinline__ float sigm_fast(float a) {
    return rcp_hw(1.0f + exp2_hw(a * -1.4426950408889634f));
}
__device__ __forceinline__ float tanh_fast(float a) {
    return fmaf(2.0f, rcp_hw(1.0f + exp2_hw(a * -2.8853900817779268f)), -1.0f);
}

__global__ __launch_bounds__(256) void lstm_p16_kernel(
    const float* __restrict__ x,   const float* __restrict__ Wih,
    const float* __restrict__ Whh, const float* __restrict__ bih,
    const float* __restrict__ bhh, const float* __restrict__ W1,
    const float* __restrict__ b1v, const float* __restrict__ W2,
    const float* __restrict__ b2v, float* __restrict__ out)
{
    const int lane  = threadIdx.x & 63;
    const int s     = lane & 15;          // slot within 16-lane batch group
    const bool isP1 = (s >= 8);           // p=0: gates i,f ; p=1: gates g,o
    const int d6    = s & 7;
    const int d     = (d6 < 6) ? d6 : 5;  // hidden unit owned (lanes 6,7 dup d=5)
    const int wid   = (blockIdx.x * 256 + threadIdx.x) >> 6;
    const int b     = wid * 4 + (lane >> 4);

    // gate rows owned by this lane (PyTorch order i,f,g,o)
    const int r0 = (isP1 ? 12 : 0) + d;   // i or g
    const int r1 = (isP1 ? 18 : 6) + d;   // f or o

    f32x2 wpk[12], bias2;
    #pragma unroll
    for (int k = 0; k < 6; ++k) {
        wpk[k].x     = Wih[r0 * 6 + k]; wpk[k].y     = Wih[r1 * 6 + k];
        wpk[6 + k].x = Whh[r0 * 6 + k]; wpk[6 + k].y = Whh[r1 * 6 + k];
    }
    bias2.x = bih[r0] + bhh[r0];
    bias2.y = bih[r1] + bhh[r1];

    // e0 activation params: sigmoid (p=0, i-gate) or tanh (p=1, g-gate)
    const float em0 = isP1 ? -2.8853900817779268f : -1.4426950408889634f;
    const float am0 = isP1 ? 2.0f : 1.0f;
    const float cm0 = isP1 ? -1.0f : 0.0f;

    // bpermute byte indices (within-wave lane*4)
    const int gb   = lane & ~15;
    const int idxO = (lane ^ 8) << 2;     // opposite-half partner, same d
    const int ih0 = (gb +  8) << 2, ih1 = (gb +  9) << 2, ih2 = (gb + 10) << 2;
    const int ih3 = (gb + 11) << 2, ih4 = (gb + 12) << 2, ih5 = (gb + 13) << 2;

    const float* xrow = x + (size_t)b * (T_STEPS * 6);

    // 4-step x prefetch pipeline: each step = 3x 8B loads of the same row
    f32x2 pfA[4], pfB[4], pfC[4];
    #pragma unroll
    for (int i = 0; i < 4; ++i) {
        pfA[i] = *(const f32x2*)(xrow + i * 6 + 0);
        pfB[i] = *(const f32x2*)(xrow + i * 6 + 2);
        pfC[i] = *(const f32x2*)(xrow + i * 6 + 4);
    }

    float c = 0.0f, h = 0.0f;

    auto step = [&](int slot, int t) {
        // h broadcast from p=1 lanes (the on-chain LDS op) — issue first
        f32x2 ha, hb, hc;
        ha.x = bperm(ih0, h); ha.y = bperm(ih1, h);
        hb.x = bperm(ih2, h); hb.y = bperm(ih3, h);
        hc.x = bperm(ih4, h); hc.y = bperm(ih5, h);

        const f32x2 xa = pfA[slot], xb = pfB[slot], xc = pfC[slot];
        int tn = t + 4; if (tn >= T_STEPS) tn = T_STEPS - 1;
        pfA[slot] = *(const f32x2*)(xrow + tn * 6 + 0);
        pfB[slot] = *(const f32x2*)(xrow + tn * 6 + 2);
        pfC[slot] = *(const f32x2*)(xrow + tn * 6 + 4);

        // x-part (off the recurrence chain)
        f32x2 acc = bias2;
        pk_fma_lo(acc, wpk[0], xa); pk_fma_hi(acc, wpk[1], xa);
        pk_fma_lo(acc, wpk[2], xb); pk_fma_hi(acc, wpk[3], xb);
        pk_fma_lo(acc, wpk[4], xc); pk_fma_hi(acc, wpk[5], xc);

        // h-part: two parallel 3-deep chains
        f32x2 acc2 = {0.0f, 0.0f};
        pk_fma_lo(acc,  wpk[6],  ha);
        pk_fma_hi(acc2, wpk[7],  ha);
        pk_fma_lo(acc,  wpk[8],  hb);
        pk_fma_hi(acc2, wpk[9],  hb);
        pk_fma_lo(acc,  wpk[10], hc);
        pk_fma_hi(acc2, wpk[11], hc);

        const float g0 = acc.x + acc2.x;   // preact of gate r0 (i or g)
        const float g1 = acc.y + acc2.y;   // preact of gate r1 (f or o)

        const float e0 = fmaf(am0, rcp_hw(1.0f + exp2_hw(g0 * em0)), cm0);
        const float e1 = sigm_fast(g1);

        // exchange with opposite half (both halves compute c redundantly)
        const float pa = bperm(idxO, e0);  // p=0 gets g ; p=1 gets i
        const float pb = bperm(idxO, e1);  // p=0 gets o (unused) ; p=1 gets f

        // iv*gv == e0*pa on BOTH halves; only f needs a select
        const float fv = isP1 ? pb : e1;
        c = fmaf(fv, c, e0 * pa);
        const float tc = tanh_fast(c);
        h = e1 * tc;                        // valid h on p=1 lanes (o * tanh(c))
    };

    for (int t = 0; t < T_STEPS; t += 4) {
        step(0, t); step(1, t + 1); step(2, t + 2); step(3, t + 3);
    }

    // --- head: gather h, compute 6->4->2->softmax redundantly, store from s==0 ---
    float hf[6];
    hf[0] = bperm(ih0, h); hf[1] = bperm(ih1, h); hf[2] = bperm(ih2, h);
    hf[3] = bperm(ih3, h); hf[4] = bperm(ih4, h); hf[5] = bperm(ih5, h);

    float o1[4];
    #pragma unroll
    for (int j = 0; j < 4; ++j) {
        float a = b1v[j];
        #pragma unroll
        for (int k = 0; k < 6; ++k) a = fmaf(W1[j * 6 + k], hf[k], a);
        o1[j] = a;
    }
    float o2[2];
    #pragma unroll
    for (int m = 0; m < 2; ++m) {
        float a = b2v[m];
        #pragma unroll
        for (int j = 0; j < 4; ++j) a = fmaf(W2[m * 4 + j], o1[j], a);
        o2[m] = a;
    }
    const float mx = fmaxf(o2[0], o2[1]);
    const float e0s = exp2_hw((o2[0] - mx) * 1.4426950408889634f);
    const float e1s = exp2_hw((o2[1] - mx) * 1.4426950408889634f);
    const float sc  = rcp_hw(e0s + e1s);

    if (s == 0) {
        ((float2*)out)[b] = make_float2(e0s * sc, e1s * sc);
    }
}

extern "C" void kernel_launch(void* const* d_in, const int* in_sizes, int n_in,
                              void* d_out, int out_size, void* d_ws, size_t ws_size,
                              hipStream_t stream) {
    const float* x   = (const float*)d_in[0];
    const float* Wih = (const float*)d_in[1];
    const float* Whh = (const float*)d_in[2];
    const float* bih = (const float*)d_in[3];
    const float* bhh = (const float*)d_in[4];
    const float* W1  = (const float*)d_in[5];
    const float* b1v = (const float*)d_in[6];
    const float* W2  = (const float*)d_in[7];
    const float* b2v = (const float*)d_in[8];
    float* out = (float*)d_out;

    // 16 lanes/batch, 4 batch/wave, 4 waves/block -> 16 batch/block -> 512 blocks
    // 2048 waves total = 2 waves/SIMD on 256 CUs.
    const int blocks = BATCH / 16;
    lstm_p16_kernel<<<blocks, 256, 0, stream>>>(x, Wih, Whh, bih, bhh, W1, b1v, W2, b2v, out);
}

// Round 4
// 135.445 us; speedup vs baseline: 1.2005x; 1.2005x over previous
//
#include <hip/hip_runtime.h>

#define T_STEPS 512
#define BATCH   8192

typedef float f32x2 __attribute__((ext_vector_type(2)));

__device__ __forceinline__ float rcp_hw(float v)  { return __builtin_amdgcn_rcpf(v); }
__device__ __forceinline__ float exp2_hw(float v) { return __builtin_amdgcn_exp2f(v); }

// DPP cross-lane move (VALU pipe, no LDS). CTRL is compile-time.
template<int CTRL>
__device__ __forceinline__ float dpp_mov(float v) {
    return __int_as_float(__builtin_amdgcn_mov_dpp(__float_as_int(v), CTRL, 0xF, 0xF, true));
}
#define QP_BCAST0 0x00   // quad_perm [0,0,0,0]
#define QP_BCAST2 0xAA   // quad_perm [2,2,2,2]
#define QP_SWAP1  0xB1   // quad_perm [1,0,3,2]  (lane^1)
#define ROW_HALF_MIRROR 0x141  // lane^7  -> quad^1 (quad-uniform data)
#define ROW_ROR8        0x128  // lane^8  -> quad^2 (rot by 8 == xor 8)
#define ROW_MIRROR      0x140  // lane^15 -> quad^3

// one-time head gather: broadcast lane 2K of each 16-lane group
template<int K>
__device__ __forceinline__ float swz16(float v) {
    return __int_as_float(__builtin_amdgcn_ds_swizzle(__float_as_int(v), ((2*K) << 5) | 0x10));
}

// acc += wpk * broadcast(b.lo / b.hi)   (verified in R2)
__device__ __forceinline__ void pk_fma_lo(f32x2& d, f32x2 a, f32x2 b) {
    asm("v_pk_fma_f32 %0, %1, %2, %0 op_sel:[0,0,0] op_sel_hi:[1,0,1]"
        : "+v"(d) : "v"(a), "v"(b));
}
__device__ __forceinline__ void pk_fma_hi(f32x2& d, f32x2 a, f32x2 b) {
    asm("v_pk_fma_f32 %0, %1, %2, %0 op_sel:[0,1,0] op_sel_hi:[1,1,1]"
        : "+v"(d) : "v"(a), "v"(b));
}
__device__ __forceinline__ void pk_add(f32x2& d, f32x2 a) {
    asm("v_pk_add_f32 %0, %0, %1" : "+v"(d) : "v"(a));
}

__global__ __launch_bounds__(256) void lstm_dpp_kernel(
    const float* __restrict__ x,   const float* __restrict__ Wih,
    const float* __restrict__ Whh, const float* __restrict__ bih,
    const float* __restrict__ bhh, const float* __restrict__ W1,
    const float* __restrict__ b1v, const float* __restrict__ W2,
    const float* __restrict__ b2v, float* __restrict__ out)
{
    const int lane = threadIdx.x & 63;
    const int s    = lane & 15;        // slot within 16-lane batch group
    const int p    = s & 1;            // 0: gates {i,f}, 1: gates {g,o}
    const int pi   = s >> 1;           // pair index 0..7
    const int q    = (s >> 2) & 3;     // quad within group
    const int d    = (pi < 6) ? pi : pi - 2;   // hidden unit (pairs 6,7 dup 4,5)
    const int wid  = (blockIdx.x * 256 + threadIdx.x) >> 6;
    const int b    = wid * 4 + (lane >> 4);

    // gate rows (PyTorch order i,f,g,o)
    const int r0 = (p ? 12 : 0) + d;   // i or g
    const int r1 = (p ? 18 : 6) + d;   // f or o

    f32x2 wx[6], wh[8], bias2;
    #pragma unroll
    for (int k = 0; k < 6; ++k) { wx[k].x = Wih[r0 * 6 + k]; wx[k].y = Wih[r1 * 6 + k]; }
    bias2.x = bih[r0] + bhh[r0];
    bias2.y = bih[r1] + bhh[r1];
    // h arrival slot j holds units of quad q^j; zero weights for the dup quad (q^j==3)
    #pragma unroll
    for (int j = 0; j < 4; ++j) {
        const int m = q ^ j;
        const int u0 = 2 * m, u1 = 2 * m + 1;
        if (u0 < 6) { wh[2*j].x = Whh[r0*6 + u0]; wh[2*j].y = Whh[r1*6 + u0]; }
        else        { wh[2*j].x = 0.0f;           wh[2*j].y = 0.0f; }
        if (u1 < 6) { wh[2*j+1].x = Whh[r0*6 + u1]; wh[2*j+1].y = Whh[r1*6 + u1]; }
        else        { wh[2*j+1].x = 0.0f;           wh[2*j+1].y = 0.0f; }
    }

    // activation consts for gate r0: sigmoid (i) or tanh (g)
    const float em0 = p ? -2.8853900817779268f : -1.4426950408889634f;
    const float am0 = p ? 2.0f : 1.0f;
    const float cm0 = p ? -1.0f : 0.0f;

    const float* xrow = x + (size_t)b * (T_STEPS * 6);

    // 4-step prefetch pipeline (each lane loads the full 24B x-row)
    f32x2 pfA[4], pfB[4], pfC[4];
    #pragma unroll
    for (int i = 0; i < 4; ++i) {
        pfA[i] = *(const f32x2*)(xrow + i * 6 + 0);
        pfB[i] = *(const f32x2*)(xrow + i * 6 + 2);
        pfC[i] = *(const f32x2*)(xrow + i * 6 + 4);
    }

    // accx for step 0 (bias + Wih·x0)
    f32x2 accA = bias2, accB;
    pk_fma_lo(accA, wx[0], pfA[0]); pk_fma_hi(accA, wx[1], pfA[0]);
    pk_fma_lo(accA, wx[2], pfB[0]); pk_fma_hi(accA, wx[3], pfB[0]);
    pk_fma_lo(accA, wx[4], pfC[0]); pk_fma_hi(accA, wx[5], pfC[0]);

    float c = 0.0f, h = 0.0f;

    auto step = [&](int slot, int t, f32x2& axc, f32x2& axn) {
        // --- h gather: 8 DPP movs, all-VALU, quad-uniform packed pairs ---
        f32x2 P, P1, P2, P3;
        P.x  = dpp_mov<QP_BCAST0>(h);        // own quad, even pair
        P.y  = dpp_mov<QP_BCAST2>(h);        // own quad, odd pair
        P1.x = dpp_mov<ROW_HALF_MIRROR>(P.x); P1.y = dpp_mov<ROW_HALF_MIRROR>(P.y); // quad^1
        P2.x = dpp_mov<ROW_ROR8>(P.x);        P2.y = dpp_mov<ROW_ROR8>(P.y);        // quad^2
        P3.x = dpp_mov<ROW_MIRROR>(P.x);      P3.y = dpp_mov<ROW_MIRROR>(P.y);      // quad^3

        // --- h-part: two 4-deep packed FMA chains ---
        f32x2 acc = axc, acc2; acc2.x = 0.0f; acc2.y = 0.0f;
        pk_fma_lo(acc,  wh[0], P);  pk_fma_hi(acc2, wh[1], P);
        pk_fma_lo(acc,  wh[2], P1); pk_fma_hi(acc2, wh[3], P1);
        pk_fma_lo(acc,  wh[4], P2); pk_fma_hi(acc2, wh[5], P2);
        pk_fma_lo(acc,  wh[6], P3); pk_fma_hi(acc2, wh[7], P3);

        // --- x-part for step t+1 (independent; fills act-chain stalls) ---
        const int sl1 = (slot + 1) & 3;
        const f32x2 xa = pfA[sl1], xb = pfB[sl1], xc = pfC[sl1];
        axn = bias2;
        pk_fma_lo(axn, wx[0], xa); pk_fma_hi(axn, wx[1], xa);
        pk_fma_lo(axn, wx[2], xb); pk_fma_hi(axn, wx[3], xb);
        pk_fma_lo(axn, wx[4], xc); pk_fma_hi(axn, wx[5], xc);

        // prefetch x(t+4)
        int tn = t + 4; if (tn >= T_STEPS) tn = T_STEPS - 1;
        pfA[slot] = *(const f32x2*)(xrow + tn * 6 + 0);
        pfB[slot] = *(const f32x2*)(xrow + tn * 6 + 2);
        pfC[slot] = *(const f32x2*)(xrow + tn * 6 + 4);

        pk_add(acc, acc2);

        // --- activations ---
        const float e0 = fmaf(am0, rcp_hw(1.0f + exp2_hw(acc.x * em0)), cm0); // i or g
        const float e1 = rcp_hw(1.0f + exp2_hw(acc.y * -1.4426950408889634f)); // f or o

        // --- pair exchange on VALU (lane^1) ---
        const float pa = dpp_mov<QP_SWAP1>(e0);  // p0 gets g, p1 gets i
        const float pb = dpp_mov<QP_SWAP1>(e1);  // p0 gets o, p1 gets f

        const float fv = p ? pb : e1;
        c = fmaf(fv, c, e0 * pa);                // i*g == e0*pa on both halves
        const float th = fmaf(2.0f, rcp_hw(1.0f + exp2_hw(c * -2.8853900817779268f)), -1.0f);
        const float ov = p ? e1 : pb;
        h = ov * th;                              // both pair lanes hold h_d
    };

    for (int t = 0; t < T_STEPS; t += 4) {
        step(0, t + 0, accA, accB);
        step(1, t + 1, accB, accA);
        step(2, t + 2, accA, accB);
        step(3, t + 3, accB, accA);
    }

    // --- head: one-time gather of h0..h5, 6->4->2->softmax, store from s==0 ---
    float hf[6];
    hf[0] = swz16<0>(h); hf[1] = swz16<1>(h); hf[2] = swz16<2>(h);
    hf[3] = swz16<3>(h); hf[4] = swz16<4>(h); hf[5] = swz16<5>(h);

    float o1[4];
    #pragma unroll
    for (int j = 0; j < 4; ++j) {
        float a = b1v[j];
        #pragma unroll
        for (int k = 0; k < 6; ++k) a = fmaf(W1[j * 6 + k], hf[k], a);
        o1[j] = a;
    }
    float o2[2];
    #pragma unroll
    for (int m = 0; m < 2; ++m) {
        float a = b2v[m];
        #pragma unroll
        for (int j = 0; j < 4; ++j) a = fmaf(W2[m * 4 + j], o1[j], a);
        o2[m] = a;
    }
    const float mx  = fmaxf(o2[0], o2[1]);
    const float e0s = exp2_hw((o2[0] - mx) * 1.4426950408889634f);
    const float e1s = exp2_hw((o2[1] - mx) * 1.4426950408889634f);
    const float sc  = rcp_hw(e0s + e1s);

    if (s == 0) {
        ((float2*)out)[b] = make_float2(e0s * sc, e1s * sc);
    }
}

extern "C" void kernel_launch(void* const* d_in, const int* in_sizes, int n_in,
                              void* d_out, int out_size, void* d_ws, size_t ws_size,
                              hipStream_t stream) {
    const float* x   = (const float*)d_in[0];
    const float* Wih = (const float*)d_in[1];
    const float* Whh = (const float*)d_in[2];
    const float* bih = (const float*)d_in[3];
    const float* bhh = (const float*)d_in[4];
    const float* W1  = (const float*)d_in[5];
    const float* b1v = (const float*)d_in[6];
    const float* W2  = (const float*)d_in[7];
    const float* b2v = (const float*)d_in[8];
    float* out = (float*)d_out;

    // 16 lanes/batch, 4 batch/wave, 4 waves/block -> 512 blocks = 2048 waves
    // = 2 waves/SIMD on 256 CUs.
    const int blocks = BATCH / 16;
    lstm_dpp_kernel<<<blocks, 256, 0, stream>>>(x, Wih, Whh, bih, bhh, W1, b1v, W2, b2v, out);
}